// Round 6
// baseline (358.309 us; speedup 1.0000x reference)
//
#include <hip/hip_runtime.h>
#include <hip/hip_bf16.h>
#include <math.h>

#define N_NODES 20000
#define N_EDGES 320000
#define DIM 512
#define HEADS 4
#define DHEAD 128
#define NEG_SLOPE 0.2f
#define BM 64
#define BN 64
#define BK 64

typedef __attribute__((ext_vector_type(8))) short short8;
typedef __attribute__((ext_vector_type(8))) __bf16 bf16x8;
typedef __attribute__((ext_vector_type(4))) float f32x4;

static __device__ __forceinline__ unsigned short f32_to_bf16(float f) {
    union { float f; unsigned u; } v; v.f = f;
    unsigned u = v.u;
    u += 0x7FFFu + ((u >> 16) & 1u);   // round-to-nearest-even
    return (unsigned short)(u >> 16);
}
static __device__ __forceinline__ float bf16_to_f32(unsigned short s) {
    union { unsigned u; float f; } v; v.u = ((unsigned)s) << 16;
    return v.f;
}
static __device__ __forceinline__ float bits_f32(unsigned u) {
    union { unsigned u; float f; } v; v.u = u;
    return v.f;
}

static __device__ __forceinline__ void gl_lds16(const unsigned short* g, unsigned short* l) {
    __builtin_amdgcn_global_load_lds(
        (const __attribute__((address_space(1))) unsigned int*)g,
        (__attribute__((address_space(3))) unsigned int*)l, 16, 0, 0);
}

// ---------------- CSR build ----------------
__global__ void k_hist(const int* __restrict__ dst, int* __restrict__ counts) {
    int e = blockIdx.x * blockDim.x + threadIdx.x;
    if (e >= N_EDGES) return;
    atomicAdd(&counts[dst[e]], 1);
}

__global__ void k_scan(const int* __restrict__ counts, int* __restrict__ offsets,
                       int* __restrict__ cursor) {
    __shared__ int lds[1024];
    int t = threadIdx.x;
    const int CH = (N_NODES + 1023) / 1024;   // 20
    int base = t * CH;
    int sum = 0;
    for (int j = 0; j < CH; j++) {
        int i = base + j;
        if (i < N_NODES) sum += counts[i];
    }
    lds[t] = sum;
    __syncthreads();
    for (int off = 1; off < 1024; off <<= 1) {
        int other = (t >= off) ? lds[t - off] : 0;
        __syncthreads();
        lds[t] += other;
        __syncthreads();
    }
    int excl = lds[t] - sum;
    int run = excl;
    for (int j = 0; j < CH; j++) {
        int i = base + j;
        if (i < N_NODES) {
            offsets[i] = run;
            cursor[i] = run;
            run += counts[i];
        }
    }
    if (t == 0) offsets[N_NODES] = N_EDGES;
}

__global__ void k_fill(const int* __restrict__ src, const int* __restrict__ dst,
                       int* __restrict__ cursor, int* __restrict__ csr_src) {
    int e = blockIdx.x * blockDim.x + threadIdx.x;
    if (e >= N_EDGES) return;
    int d = dst[e];
    int p = atomicAdd(&cursor[d], 1);
    csr_src[p] = src[e];
}

// ---------------- split casts ----------------
__global__ void k_cast_split(const float* __restrict__ in,
                             unsigned short* __restrict__ hi,
                             unsigned short* __restrict__ lo, int n8) {
    int i = blockIdx.x * blockDim.x + threadIdx.x;
    if (i >= n8) return;
    const float4* p = reinterpret_cast<const float4*>(in) + (size_t)i * 2;
    float4 a = p[0], b = p[1];
    float f[8] = {a.x, a.y, a.z, a.w, b.x, b.y, b.z, b.w};
    short8 oh, ol;
#pragma unroll
    for (int j = 0; j < 8; j++) {
        unsigned short h = f32_to_bf16(f[j]);
        oh[j] = (short)h;
        ol[j] = (short)f32_to_bf16(f[j] - bf16_to_f32(h));
    }
    *reinterpret_cast<short8*>(hi + (size_t)i * 8) = oh;
    *reinterpret_cast<short8*>(lo + (size_t)i * 8) = ol;
}

// W: (H, D, DH) f32 -> Bt_{hi,lo}: [col][k] bf16, col=h*128+f, k over D
__global__ void k_transW(const float* __restrict__ W,
                         unsigned short* __restrict__ Bhi,
                         unsigned short* __restrict__ Blo) {
    int id = blockIdx.x * blockDim.x + threadIdx.x;
    if (id >= 512 * 64) return;
    int col = id >> 6;
    int kg = id & 63;
    int h = col >> 7;
    int f = col & 127;
    short8 oh, ol;
#pragma unroll
    for (int j = 0; j < 8; j++) {
        int k = kg * 8 + j;
        float w = W[(size_t)h * DIM * DHEAD + (size_t)k * DHEAD + f];
        unsigned short hb = f32_to_bf16(w);
        oh[j] = (short)hb;
        ol[j] = (short)f32_to_bf16(w - bf16_to_f32(hb));
    }
    *reinterpret_cast<short8*>(Bhi + (size_t)col * DIM + kg * 8) = oh;
    *reinterpret_cast<short8*>(Blo + (size_t)col * DIM + kg * 8) = ol;
}

// ---------------- small-tile high-occupancy split-bf16 GEMM + fused logits ----------------
// 64x64 tile, BK=64, 4 waves (2x2), 32KB LDS single-buffer -> 5 blocks/CU.
// LDS regions (shorts): Ah@0, Al@4096, Bh@8192, Bl@12288; row = 64 shorts = 8 slots x 16B.
// phys_slot = log_slot ^ (row&7); linear LDS dest (global_load_lds) + inverse-swizzled
// global source + swizzled ds_read (both-sides rule).
#define MFMA(a, b, c) __builtin_amdgcn_mfma_f32_16x16x32_bf16(a, b, c, 0, 0, 0)

__global__ __launch_bounds__(256, 5) void k_gemm_t(const unsigned short* __restrict__ Ahi,
                                                   const unsigned short* __restrict__ Alo,
                                                   const unsigned short* __restrict__ Bhi,
                                                   const unsigned short* __restrict__ Blo,
                                                   const float* __restrict__ avec,
                                                   unsigned short* __restrict__ Hout,
                                                   float* __restrict__ als,
                                                   float* __restrict__ ald) {
    __shared__ unsigned short lds[16384];   // 32 KB
    const int tid = threadIdx.x;

    // bijective XCD swizzle: 2504 = 8 * 313 exactly
    const int orig = blockIdx.x;
    const int wgid = (orig & 7) * 313 + (orig >> 3);
    const int mb = wgid >> 3, nb = wgid & 7;
    const int m0 = mb * BM, n0 = nb * BN;
    const int lane = tid & 63, wid = tid >> 6;
    const int wm = wid >> 1, wn = wid & 1;
    const int lr = lane & 15, kq = lane >> 4;

    f32x4 acc[2][2];
#pragma unroll
    for (int i = 0; i < 2; i++)
#pragma unroll
        for (int j = 0; j < 2; j++) acc[i][j] = (f32x4){0.f, 0.f, 0.f, 0.f};

#pragma unroll 1
    for (int t = 0; t < 8; t++) {
        const int k0 = t * BK;
        // ---- stage 32KB ----
#pragma unroll
        for (int it = 0; it < 8; it++) {
            const int region = it >> 1;              // 0=Ah 1=Al 2=Bh 3=Bl
            int c = (it & 1) * 256 + tid;            // 0..511
            int row = c >> 3;                        // 0..63
            int sl = (c & 7) ^ (row & 7);            // inverse-swizzled source slot
            int koff = k0 + sl * 8;
            const unsigned short* srcp;
            if (region == 0) {
                int ar = m0 + row; ar = ar < N_NODES ? ar : N_NODES - 1;
                srcp = Ahi + (size_t)ar * DIM + koff;
            } else if (region == 1) {
                int ar = m0 + row; ar = ar < N_NODES ? ar : N_NODES - 1;
                srcp = Alo + (size_t)ar * DIM + koff;
            } else if (region == 2) {
                srcp = Bhi + (size_t)(n0 + row) * DIM + koff;
            } else {
                srcp = Blo + (size_t)(n0 + row) * DIM + koff;
            }
            unsigned short* lb = lds + region * 4096 + ((it & 1) * 256 + (tid & 192)) * 8;
            gl_lds16(srcp, lb);
        }
        asm volatile("s_waitcnt vmcnt(0)" ::: "memory");
        __syncthreads();

        // ---- compute ----
#pragma unroll
        for (int ks = 0; ks < 2; ks++) {
            bf16x8 ah[2], al[2], bh[2], bl[2];
#pragma unroll
            for (int tm = 0; tm < 2; tm++) {
                int row = wm * 32 + tm * 16 + lr;
                int ph = (ks * 4 + kq) ^ (row & 7);
                int off = row * 64 + ph * 8;
                ah[tm] = __builtin_bit_cast(bf16x8, *reinterpret_cast<const short8*>(lds + off));
                al[tm] = __builtin_bit_cast(bf16x8, *reinterpret_cast<const short8*>(lds + 4096 + off));
            }
#pragma unroll
            for (int tn = 0; tn < 2; tn++) {
                int col = wn * 32 + tn * 16 + lr;
                int ph = (ks * 4 + kq) ^ (col & 7);
                int off = col * 64 + ph * 8;
                bh[tn] = __builtin_bit_cast(bf16x8, *reinterpret_cast<const short8*>(lds + 8192 + off));
                bl[tn] = __builtin_bit_cast(bf16x8, *reinterpret_cast<const short8*>(lds + 12288 + off));
            }
#pragma unroll
            for (int tm = 0; tm < 2; tm++)
#pragma unroll
                for (int tn = 0; tn < 2; tn++) {
                    acc[tm][tn] = MFMA(ah[tm], bh[tn], acc[tm][tn]);
                    acc[tm][tn] = MFMA(ah[tm], bl[tn], acc[tm][tn]);
                    acc[tm][tn] = MFMA(al[tm], bh[tn], acc[tm][tn]);
                }
        }
        if (t < 7) __syncthreads();
    }

    // ---- store bf16 h ----
#pragma unroll
    for (int tm = 0; tm < 2; tm++)
#pragma unroll
        for (int tn = 0; tn < 2; tn++) {
            int col = n0 + wn * 32 + tn * 16 + lr;
#pragma unroll
            for (int r4 = 0; r4 < 4; r4++) {
                int row = m0 + wm * 32 + tm * 16 + kq * 4 + r4;
                if (row < N_NODES) Hout[(size_t)row * DIM + col] = f32_to_bf16(acc[tm][tn][r4]);
            }
        }

    // ---- fused attention logits from f32 accumulators (exact h) ----
    const int head = nb >> 1;
    const float* asrc = avec + head * 2 * DHEAD;
    const float* adst = asrc + DHEAD;
    float ps[2][4], pd[2][4];
#pragma unroll
    for (int tm = 0; tm < 2; tm++)
#pragma unroll
        for (int r4 = 0; r4 < 4; r4++) { ps[tm][r4] = 0.f; pd[tm][r4] = 0.f; }
#pragma unroll
    for (int tn = 0; tn < 2; tn++) {
        int f = (nb & 1) * 64 + wn * 32 + tn * 16 + lr;
        float As = asrc[f];
        float Ad = adst[f];
#pragma unroll
        for (int tm = 0; tm < 2; tm++)
#pragma unroll
            for (int r4 = 0; r4 < 4; r4++) {
                ps[tm][r4] += acc[tm][tn][r4] * As;
                pd[tm][r4] += acc[tm][tn][r4] * Ad;
            }
    }
#pragma unroll
    for (int off = 1; off < 16; off <<= 1)
#pragma unroll
        for (int tm = 0; tm < 2; tm++)
#pragma unroll
            for (int r4 = 0; r4 < 4; r4++) {
                ps[tm][r4] += __shfl_xor(ps[tm][r4], off);
                pd[tm][r4] += __shfl_xor(pd[tm][r4], off);
            }
    if (lr == 0) {
#pragma unroll
        for (int tm = 0; tm < 2; tm++)
#pragma unroll
            for (int r4 = 0; r4 < 4; r4++) {
                int row = m0 + wm * 32 + tm * 16 + kq * 4 + r4;
                if (row < N_NODES) {
                    atomicAdd(&als[row * 4 + head], ps[tm][r4]);
                    atomicAdd(&ald[row * 4 + head], pd[tm][r4]);
                }
            }
    }
}

// ---------------- single-pass softmax-free aggregation ----------------
// wave = (node v, half hf); lane covers 4 cols at c0 = hf*256 + lane*4 (one head).
// alpha = exp(leaky(e)) / sum(exp(leaky(e)))  (no max subtraction: |e| <= ~45 << 88)
#define EDGE_STEP(uu, ee, w0, w1)                                           \
    {                                                                       \
        float sc_ = (ee) + aldh;                                            \
        sc_ = fmaxf(sc_, NEG_SLOPE * sc_);                                  \
        float w_ = __expf(sc_);                                             \
        s += w_;                                                            \
        acc0 += w_ * bits_f32((w0) << 16);                                  \
        acc1 += w_ * bits_f32((w0) & 0xFFFF0000u);                          \
        acc2 += w_ * bits_f32((w1) << 16);                                  \
        acc3 += w_ * bits_f32((w1) & 0xFFFF0000u);                          \
    }

__global__ __launch_bounds__(256) void k_agg(const int* __restrict__ offsets,
                                             const int* __restrict__ csr_src,
                                             const float* __restrict__ als,
                                             const float* __restrict__ ald,
                                             const unsigned short* __restrict__ H,
                                             const float* __restrict__ bias,
                                             const float* __restrict__ resid,
                                             float* __restrict__ out_f32,
                                             unsigned short* __restrict__ out_hi,
                                             unsigned short* __restrict__ out_lo) {
    int gw = (blockIdx.x * blockDim.x + threadIdx.x) >> 6;
    if (gw >= N_NODES * 2) return;
    int v = gw >> 1;
    int hf = gw & 1;
    int lane = threadIdx.x & 63;
    int c0 = hf * 256 + lane * 4;
    int hd = c0 >> 7;

    int beg = offsets[v], deg = offsets[v + 1] - beg;
    float aldh = ald[v * 4 + hd];
    const int* cp = csr_src + beg;

    float acc0 = 0.f, acc1 = 0.f, acc2 = 0.f, acc3 = 0.f, s = 0.f;
    int i = 0;
    for (; i + 4 <= deg; i += 4) {
        int u0 = cp[i], u1 = cp[i + 1], u2 = cp[i + 2], u3 = cp[i + 3];
        float e0 = als[u0 * 4 + hd];
        float e1 = als[u1 * 4 + hd];
        float e2 = als[u2 * 4 + hd];
        float e3 = als[u3 * 4 + hd];
        uint2 h0 = *reinterpret_cast<const uint2*>(H + (size_t)u0 * DIM + c0);
        uint2 h1 = *reinterpret_cast<const uint2*>(H + (size_t)u1 * DIM + c0);
        uint2 h2 = *reinterpret_cast<const uint2*>(H + (size_t)u2 * DIM + c0);
        uint2 h3 = *reinterpret_cast<const uint2*>(H + (size_t)u3 * DIM + c0);
        EDGE_STEP(u0, e0, h0.x, h0.y);
        EDGE_STEP(u1, e1, h1.x, h1.y);
        EDGE_STEP(u2, e2, h2.x, h2.y);
        EDGE_STEP(u3, e3, h3.x, h3.y);
    }
    for (; i < deg; i++) {
        int u0 = cp[i];
        float e0 = als[u0 * 4 + hd];
        uint2 h0 = *reinterpret_cast<const uint2*>(H + (size_t)u0 * DIM + c0);
        EDGE_STEP(u0, e0, h0.x, h0.y);
    }

    float inv = deg > 0 ? 1.0f / s : 0.f;
    float4 bv = *reinterpret_cast<const float4*>(bias + c0);
    float4 rv = *reinterpret_cast<const float4*>(resid + (size_t)v * DIM + c0);
    float o0 = acc0 * inv + bv.x;
    float o1 = acc1 * inv + bv.y;
    float o2 = acc2 * inv + bv.z;
    float o3 = acc3 * inv + bv.w;
    o0 = o0 > 0.f ? o0 : expm1f(o0);
    o1 = o1 > 0.f ? o1 : expm1f(o1);
    o2 = o2 > 0.f ? o2 : expm1f(o2);
    o3 = o3 > 0.f ? o3 : expm1f(o3);
    o0 += rv.x; o1 += rv.y; o2 += rv.z; o3 += rv.w;
    float4 ov = {o0, o1, o2, o3};
    *reinterpret_cast<float4*>(out_f32 + (size_t)v * DIM + c0) = ov;
    if (out_hi) {
        unsigned short hb0 = f32_to_bf16(o0), hb1 = f32_to_bf16(o1);
        unsigned short hb2 = f32_to_bf16(o2), hb3 = f32_to_bf16(o3);
        ushort4 oh = {hb0, hb1, hb2, hb3};
        ushort4 ol = {f32_to_bf16(o0 - bf16_to_f32(hb0)), f32_to_bf16(o1 - bf16_to_f32(hb1)),
                      f32_to_bf16(o2 - bf16_to_f32(hb2)), f32_to_bf16(o3 - bf16_to_f32(hb3))};
        *reinterpret_cast<ushort4*>(out_hi + (size_t)v * DIM + c0) = oh;
        *reinterpret_cast<ushort4*>(out_lo + (size_t)v * DIM + c0) = ol;
    }
}

extern "C" void kernel_launch(void* const* d_in, const int* in_sizes, int n_in,
                              void* d_out, int out_size, void* d_ws, size_t ws_size,
                              hipStream_t stream) {
    const float* x = (const float*)d_in[0];
    const int* ei = (const int*)d_in[1];
    const int* src = ei;
    const int* dst = ei + N_EDGES;
    const float* W1 = (const float*)d_in[5];
    const float* a1 = (const float*)d_in[6];
    const float* b1 = (const float*)d_in[7];
    const float* W2 = (const float*)d_in[8];
    const float* a2 = (const float*)d_in[9];
    const float* b2 = (const float*)d_in[10];

    char* ws = (char*)d_ws;
    size_t off = 0;
    auto alloc = [&](size_t bytes) -> void* {
        void* p = ws + off;
        off += (bytes + 255) & ~(size_t)255;
        return p;
    };
    unsigned short* xhi  = (unsigned short*)alloc((size_t)N_NODES * DIM * 2);
    unsigned short* xlo  = (unsigned short*)alloc((size_t)N_NODES * DIM * 2);
    unsigned short* h    = (unsigned short*)alloc((size_t)N_NODES * DIM * 2);
    float* x1            = (float*)alloc((size_t)N_NODES * DIM * 4);
    float* als           = (float*)alloc((size_t)N_NODES * 8 * 4);  // als | ald contiguous
    float* ald           = als + (size_t)N_NODES * 4;
    unsigned short* B1h  = (unsigned short*)alloc((size_t)DIM * DIM * 2);
    unsigned short* B1l  = (unsigned short*)alloc((size_t)DIM * DIM * 2);
    unsigned short* B2h  = (unsigned short*)alloc((size_t)DIM * DIM * 2);
    unsigned short* B2l  = (unsigned short*)alloc((size_t)DIM * DIM * 2);
    int* offsets         = (int*)alloc((size_t)(N_NODES + 1) * 4);
    int* cursor          = (int*)alloc((size_t)N_NODES * 4);
    int* counts          = (int*)alloc((size_t)N_NODES * 4);
    int* csr_src         = (int*)alloc((size_t)N_EDGES * 4);

    // CSR build (shared by both layers)
    hipMemsetAsync(counts, 0, (size_t)N_NODES * 4, stream);
    k_hist<<<(N_EDGES + 255) / 256, 256, 0, stream>>>(dst, counts);
    k_scan<<<1, 1024, 0, stream>>>(counts, offsets, cursor);
    k_fill<<<(N_EDGES + 255) / 256, 256, 0, stream>>>(src, dst, cursor, csr_src);

    // casts / weight prep
    k_cast_split<<<(N_NODES * DIM / 8 + 255) / 256, 256, 0, stream>>>(x, xhi, xlo, N_NODES * DIM / 8);
    k_transW<<<(512 * 64 + 255) / 256, 256, 0, stream>>>(W1, B1h, B1l);
    k_transW<<<(512 * 64 + 255) / 256, 256, 0, stream>>>(W2, B2h, B2l);

    const int GEMM_BLOCKS = ((N_NODES + BM - 1) / BM) * (DIM / BN);  // 313 * 8 = 2504
    const int AGG_BLOCKS = (N_NODES * 2 + 3) / 4;                    // 10000

    // ---- layer 1 ----
    hipMemsetAsync(als, 0, (size_t)N_NODES * 8 * 4, stream);
    k_gemm_t<<<GEMM_BLOCKS, 256, 0, stream>>>(xhi, xlo, B1h, B1l, a1, h, als, ald);
    k_agg<<<AGG_BLOCKS, 256, 0, stream>>>(offsets, csr_src, als, ald, h, b1, x, x1, xhi, xlo);

    // ---- layer 2 ----
    hipMemsetAsync(als, 0, (size_t)N_NODES * 8 * 4, stream);
    k_gemm_t<<<GEMM_BLOCKS, 256, 0, stream>>>(xhi, xlo, B2h, B2l, a2, h, als, ald);
    k_agg<<<AGG_BLOCKS, 256, 0, stream>>>(offsets, csr_src, als, ald, h, b2, x1, (float*)d_out, nullptr, nullptr);
}

// Round 7
// 297.309 us; speedup vs baseline: 1.2052x; 1.2052x over previous
//
#include <hip/hip_runtime.h>
#include <hip/hip_bf16.h>
#include <math.h>

#define N_NODES 20000
#define N_EDGES 320000
#define DIM 512
#define HEADS 4
#define DHEAD 128
#define NEG_SLOPE 0.2f
#define BM 64
#define BN 64
#define BK 64

typedef __attribute__((ext_vector_type(8))) short short8;
typedef __attribute__((ext_vector_type(8))) __bf16 bf16x8;
typedef __attribute__((ext_vector_type(4))) float f32x4;

static __device__ __forceinline__ unsigned short f32_to_bf16(float f) {
    union { float f; unsigned u; } v; v.f = f;
    unsigned u = v.u;
    u += 0x7FFFu + ((u >> 16) & 1u);   // round-to-nearest-even
    return (unsigned short)(u >> 16);
}
static __device__ __forceinline__ float bf16_to_f32(unsigned short s) {
    union { unsigned u; float f; } v; v.u = ((unsigned)s) << 16;
    return v.f;
}
static __device__ __forceinline__ float bits_f32(unsigned u) {
    union { unsigned u; float f; } v; v.u = u;
    return v.f;
}

static __device__ __forceinline__ void gl_lds16(const unsigned short* g, unsigned short* l) {
    __builtin_amdgcn_global_load_lds(
        (const __attribute__((address_space(1))) unsigned int*)g,
        (__attribute__((address_space(3))) unsigned int*)l, 16, 0, 0);
}

// ---------------- CSR build ----------------
__global__ void k_hist(const int* __restrict__ dst, int* __restrict__ counts) {
    int e = blockIdx.x * blockDim.x + threadIdx.x;
    if (e >= N_EDGES) return;
    atomicAdd(&counts[dst[e]], 1);
}

__global__ void k_scan(const int* __restrict__ counts, int* __restrict__ offsets,
                       int* __restrict__ cursor) {
    __shared__ int lds[1024];
    int t = threadIdx.x;
    const int CH = (N_NODES + 1023) / 1024;   // 20
    int base = t * CH;
    int sum = 0;
    for (int j = 0; j < CH; j++) {
        int i = base + j;
        if (i < N_NODES) sum += counts[i];
    }
    lds[t] = sum;
    __syncthreads();
    for (int off = 1; off < 1024; off <<= 1) {
        int other = (t >= off) ? lds[t - off] : 0;
        __syncthreads();
        lds[t] += other;
        __syncthreads();
    }
    int excl = lds[t] - sum;
    int run = excl;
    for (int j = 0; j < CH; j++) {
        int i = base + j;
        if (i < N_NODES) {
            offsets[i] = run;
            cursor[i] = run;
            run += counts[i];
        }
    }
    if (t == 0) offsets[N_NODES] = N_EDGES;
}

__global__ void k_fill(const int* __restrict__ src, const int* __restrict__ dst,
                       int* __restrict__ cursor, int* __restrict__ csr_src) {
    int e = blockIdx.x * blockDim.x + threadIdx.x;
    if (e >= N_EDGES) return;
    int d = dst[e];
    int p = atomicAdd(&cursor[d], 1);
    csr_src[p] = src[e];
}

// ---------------- cast x -> bf16 row-major ----------------
__global__ void k_cast(const float* __restrict__ in, unsigned short* __restrict__ out, int n8) {
    int i = blockIdx.x * blockDim.x + threadIdx.x;
    if (i >= n8) return;
    const float4* p = reinterpret_cast<const float4*>(in) + (size_t)i * 2;
    float4 a = p[0], b = p[1];
    short8 o;
    o[0] = (short)f32_to_bf16(a.x); o[1] = (short)f32_to_bf16(a.y);
    o[2] = (short)f32_to_bf16(a.z); o[3] = (short)f32_to_bf16(a.w);
    o[4] = (short)f32_to_bf16(b.x); o[5] = (short)f32_to_bf16(b.y);
    o[6] = (short)f32_to_bf16(b.z); o[7] = (short)f32_to_bf16(b.w);
    *reinterpret_cast<short8*>(out + (size_t)i * 8) = o;
}

// W: (H, D, DH) f32 -> Bt: [col][k] bf16, col=h*128+f, k over D
__global__ void k_transW(const float* __restrict__ W, unsigned short* __restrict__ Bt) {
    int id = blockIdx.x * blockDim.x + threadIdx.x;
    if (id >= 512 * 64) return;
    int col = id >> 6;
    int kg = id & 63;
    int h = col >> 7;
    int f = col & 127;
    short8 o;
#pragma unroll
    for (int j = 0; j < 8; j++) {
        int k = kg * 8 + j;
        o[j] = (short)f32_to_bf16(W[(size_t)h * DIM * DHEAD + (size_t)k * DHEAD + f]);
    }
    *reinterpret_cast<short8*>(Bt + (size_t)col * DIM + kg * 8) = o;
}

// ---------------- w-tilde: wt[v][k] = sum_f W[h][k][f] * a[h][sd*128+f], v=h*2+sd ----------------
__global__ void k_wtilde(const float* __restrict__ W, const float* __restrict__ a,
                         float* __restrict__ wt) {
    int id = blockIdx.x * blockDim.x + threadIdx.x;   // 4096
    if (id >= 8 * DIM) return;
    int v = id >> 9, k = id & 511;
    int h = v >> 1, sd = v & 1;
    const float* Wr = W + ((size_t)h * DIM + k) * DHEAD;
    const float* av = a + h * 2 * DHEAD + sd * DHEAD;
    float s = 0.f;
#pragma unroll 4
    for (int f = 0; f < DHEAD; f++) s += Wr[f] * av[f];
    wt[(size_t)v * DIM + k] = s;
}

// ---------------- exact f32 attention logits: als[n][h] = x[n,:]·wt[h*2], ald likewise ----------------
__global__ __launch_bounds__(256) void k_als(const float* __restrict__ x,
                                             const float* __restrict__ wt,
                                             float* __restrict__ als, float* __restrict__ ald) {
    __shared__ float wl[8 * DIM];    // 16 KB
    for (int i = threadIdx.x; i < 8 * DIM / 4; i += 256)
        reinterpret_cast<float4*>(wl)[i] = reinterpret_cast<const float4*>(wt)[i];
    __syncthreads();
    int n = blockIdx.x * 4 + (threadIdx.x >> 6);
    if (n >= N_NODES) return;
    int lane = threadIdx.x & 63;
    const float4* xp = reinterpret_cast<const float4*>(x + (size_t)n * DIM + lane * 8);
    float4 x0 = xp[0], x1 = xp[1];
    float xv[8] = {x0.x, x0.y, x0.z, x0.w, x1.x, x1.y, x1.z, x1.w};
    float p[8] = {0.f, 0.f, 0.f, 0.f, 0.f, 0.f, 0.f, 0.f};
#pragma unroll
    for (int j = 0; j < 8; j++) {
        int k = lane * 8 + j;
#pragma unroll
        for (int v = 0; v < 8; v++) p[v] += xv[j] * wl[v * DIM + k];
    }
#pragma unroll
    for (int off = 1; off < 64; off <<= 1)
#pragma unroll
        for (int v = 0; v < 8; v++) p[v] += __shfl_xor(p[v], off);
    if (lane == 0) {
        // v = h*2+sd: sd=0 -> als, sd=1 -> ald
        float4 s = {p[0], p[2], p[4], p[6]};
        float4 d = {p[1], p[3], p[5], p[7]};
        *reinterpret_cast<float4*>(als + (size_t)n * 4) = s;
        *reinterpret_cast<float4*>(ald + (size_t)n * 4) = d;
    }
}

// ---------------- plain bf16 GEMM: H[m][c] = sum_k A[m][k] * Bt[c][k] ----------------
// 64x64 tile, BK=64, 4 waves (2x2), 16KB LDS single-buffer -> 8+ blocks/CU.
// LDS: A@0, B@4096 (shorts); row = 64 shorts = 8 slots x 16B; phys = log ^ (row&7).
// Linear LDS dest (global_load_lds) + inverse-swizzled global source + swizzled ds_read.
#define MFMA(a, b, c) __builtin_amdgcn_mfma_f32_16x16x32_bf16(a, b, c, 0, 0, 0)

__global__ __launch_bounds__(256, 8) void k_gemm_t(const unsigned short* __restrict__ A,
                                                   const unsigned short* __restrict__ Bt,
                                                   unsigned short* __restrict__ Hout) {
    __shared__ unsigned short lds[8192];   // 16 KB
    const int tid = threadIdx.x;

    // bijective XCD swizzle: 2504 = 8 * 313 exactly
    const int orig = blockIdx.x;
    const int wgid = (orig & 7) * 313 + (orig >> 3);
    const int mb = wgid >> 3, nb = wgid & 7;
    const int m0 = mb * BM, n0 = nb * BN;
    const int lane = tid & 63, wid = tid >> 6;
    const int wm = wid >> 1, wn = wid & 1;
    const int lr = lane & 15, kq = lane >> 4;

    f32x4 acc[2][2];
#pragma unroll
    for (int i = 0; i < 2; i++)
#pragma unroll
        for (int j = 0; j < 2; j++) acc[i][j] = (f32x4){0.f, 0.f, 0.f, 0.f};

#pragma unroll 1
    for (int t = 0; t < 8; t++) {
        const int k0 = t * BK;
        // ---- stage 16 KB (A tile + B tile) ----
#pragma unroll
        for (int it = 0; it < 4; it++) {
            const int region = it >> 1;              // 0=A 1=B
            int c = (it & 1) * 256 + tid;            // 0..511
            int row = c >> 3;                        // 0..63
            int sl = (c & 7) ^ (row & 7);            // inverse-swizzled source slot
            int koff = k0 + sl * 8;
            const unsigned short* srcp;
            if (region == 0) {
                int ar = m0 + row; ar = ar < N_NODES ? ar : N_NODES - 1;
                srcp = A + (size_t)ar * DIM + koff;
            } else {
                srcp = Bt + (size_t)(n0 + row) * DIM + koff;
            }
            unsigned short* lb = lds + region * 4096 + ((it & 1) * 256 + (tid & 192)) * 8;
            gl_lds16(srcp, lb);
        }
        asm volatile("s_waitcnt vmcnt(0)" ::: "memory");
        __syncthreads();

        // ---- compute ----
#pragma unroll
        for (int ks = 0; ks < 2; ks++) {
            bf16x8 ah[2], bh[2];
#pragma unroll
            for (int tm = 0; tm < 2; tm++) {
                int row = wm * 32 + tm * 16 + lr;
                int ph = (ks * 4 + kq) ^ (row & 7);
                ah[tm] = __builtin_bit_cast(bf16x8,
                    *reinterpret_cast<const short8*>(lds + row * 64 + ph * 8));
            }
#pragma unroll
            for (int tn = 0; tn < 2; tn++) {
                int col = wn * 32 + tn * 16 + lr;
                int ph = (ks * 4 + kq) ^ (col & 7);
                bh[tn] = __builtin_bit_cast(bf16x8,
                    *reinterpret_cast<const short8*>(lds + 4096 + col * 64 + ph * 8));
            }
#pragma unroll
            for (int tm = 0; tm < 2; tm++)
#pragma unroll
                for (int tn = 0; tn < 2; tn++)
                    acc[tm][tn] = MFMA(ah[tm], bh[tn], acc[tm][tn]);
        }
        if (t < 7) __syncthreads();
    }

    // ---- store bf16 h ----
#pragma unroll
    for (int tm = 0; tm < 2; tm++)
#pragma unroll
        for (int tn = 0; tn < 2; tn++) {
            int col = n0 + wn * 32 + tn * 16 + lr;
#pragma unroll
            for (int r4 = 0; r4 < 4; r4++) {
                int row = m0 + wm * 32 + tm * 16 + kq * 4 + r4;
                if (row < N_NODES) Hout[(size_t)row * DIM + col] = f32_to_bf16(acc[tm][tn][r4]);
            }
        }
}

// ---------------- single-pass softmax-free aggregation ----------------
// wave = (node v, half hf); lane covers 4 cols at c0 = hf*256 + lane*4 (one head).
// alpha = exp(leaky(e)) / sum(exp(leaky(e)))  (no max subtraction: |e| <= ~45 << 88)
#define EDGE_STEP(uu, ee, w0, w1)                                           \
    {                                                                       \
        float sc_ = (ee) + aldh;                                            \
        sc_ = fmaxf(sc_, NEG_SLOPE * sc_);                                  \
        float w_ = __expf(sc_);                                             \
        s += w_;                                                            \
        acc0 += w_ * bits_f32((w0) << 16);                                  \
        acc1 += w_ * bits_f32((w0) & 0xFFFF0000u);                          \
        acc2 += w_ * bits_f32((w1) << 16);                                  \
        acc3 += w_ * bits_f32((w1) & 0xFFFF0000u);                          \
    }

__global__ __launch_bounds__(256) void k_agg(const int* __restrict__ offsets,
                                             const int* __restrict__ csr_src,
                                             const float* __restrict__ als,
                                             const float* __restrict__ ald,
                                             const unsigned short* __restrict__ H,
                                             const float* __restrict__ bias,
                                             const float* __restrict__ resid,
                                             float* __restrict__ out_f32,
                                             unsigned short* __restrict__ out_b16) {
    int gw = (blockIdx.x * blockDim.x + threadIdx.x) >> 6;
    if (gw >= N_NODES * 2) return;
    int v = gw >> 1;
    int hf = gw & 1;
    int lane = threadIdx.x & 63;
    int c0 = hf * 256 + lane * 4;
    int hd = c0 >> 7;

    int beg = offsets[v], deg = offsets[v + 1] - beg;
    float aldh = ald[v * 4 + hd];
    const int* cp = csr_src + beg;

    float acc0 = 0.f, acc1 = 0.f, acc2 = 0.f, acc3 = 0.f, s = 0.f;
    int i = 0;
    for (; i + 4 <= deg; i += 4) {
        int u0 = cp[i], u1 = cp[i + 1], u2 = cp[i + 2], u3 = cp[i + 3];
        float e0 = als[u0 * 4 + hd];
        float e1 = als[u1 * 4 + hd];
        float e2 = als[u2 * 4 + hd];
        float e3 = als[u3 * 4 + hd];
        uint2 h0 = *reinterpret_cast<const uint2*>(H + (size_t)u0 * DIM + c0);
        uint2 h1 = *reinterpret_cast<const uint2*>(H + (size_t)u1 * DIM + c0);
        uint2 h2 = *reinterpret_cast<const uint2*>(H + (size_t)u2 * DIM + c0);
        uint2 h3 = *reinterpret_cast<const uint2*>(H + (size_t)u3 * DIM + c0);
        EDGE_STEP(u0, e0, h0.x, h0.y);
        EDGE_STEP(u1, e1, h1.x, h1.y);
        EDGE_STEP(u2, e2, h2.x, h2.y);
        EDGE_STEP(u3, e3, h3.x, h3.y);
    }
    for (; i < deg; i++) {
        int u0 = cp[i];
        float e0 = als[u0 * 4 + hd];
        uint2 h0 = *reinterpret_cast<const uint2*>(H + (size_t)u0 * DIM + c0);
        EDGE_STEP(u0, e0, h0.x, h0.y);
    }

    float inv = deg > 0 ? 1.0f / s : 0.f;
    float4 bv = *reinterpret_cast<const float4*>(bias + c0);
    float4 rv = *reinterpret_cast<const float4*>(resid + (size_t)v * DIM + c0);
    float o0 = acc0 * inv + bv.x;
    float o1 = acc1 * inv + bv.y;
    float o2 = acc2 * inv + bv.z;
    float o3 = acc3 * inv + bv.w;
    o0 = o0 > 0.f ? o0 : expm1f(o0);
    o1 = o1 > 0.f ? o1 : expm1f(o1);
    o2 = o2 > 0.f ? o2 : expm1f(o2);
    o3 = o3 > 0.f ? o3 : expm1f(o3);
    o0 += rv.x; o1 += rv.y; o2 += rv.z; o3 += rv.w;
    float4 ov = {o0, o1, o2, o3};
    *reinterpret_cast<float4*>(out_f32 + (size_t)v * DIM + c0) = ov;
    if (out_b16) {
        ushort4 ob = {f32_to_bf16(o0), f32_to_bf16(o1), f32_to_bf16(o2), f32_to_bf16(o3)};
        *reinterpret_cast<ushort4*>(out_b16 + (size_t)v * DIM + c0) = ob;
    }
}

extern "C" void kernel_launch(void* const* d_in, const int* in_sizes, int n_in,
                              void* d_out, int out_size, void* d_ws, size_t ws_size,
                              hipStream_t stream) {
    const float* x = (const float*)d_in[0];
    const int* ei = (const int*)d_in[1];
    const int* src = ei;
    const int* dst = ei + N_EDGES;
    const float* W1 = (const float*)d_in[5];
    const float* a1 = (const float*)d_in[6];
    const float* b1 = (const float*)d_in[7];
    const float* W2 = (const float*)d_in[8];
    const float* a2 = (const float*)d_in[9];
    const float* b2 = (const float*)d_in[10];

    char* ws = (char*)d_ws;
    size_t off = 0;
    auto alloc = [&](size_t bytes) -> void* {
        void* p = ws + off;
        off += (bytes + 255) & ~(size_t)255;
        return p;
    };
    unsigned short* xb   = (unsigned short*)alloc((size_t)N_NODES * DIM * 2);
    unsigned short* h    = (unsigned short*)alloc((size_t)N_NODES * DIM * 2);
    float* x1            = (float*)alloc((size_t)N_NODES * DIM * 4);
    float* als           = (float*)alloc((size_t)N_NODES * 8 * 4);  // als | ald contiguous
    float* ald           = als + (size_t)N_NODES * 4;
    unsigned short* B1   = (unsigned short*)alloc((size_t)DIM * DIM * 2);
    unsigned short* B2   = (unsigned short*)alloc((size_t)DIM * DIM * 2);
    float* wt1           = (float*)alloc((size_t)8 * DIM * 4);
    float* wt2           = (float*)alloc((size_t)8 * DIM * 4);
    int* offsets         = (int*)alloc((size_t)(N_NODES + 1) * 4);
    int* cursor          = (int*)alloc((size_t)N_NODES * 4);
    int* counts          = (int*)alloc((size_t)N_NODES * 4);
    int* csr_src         = (int*)alloc((size_t)N_EDGES * 4);

    // CSR build (shared by both layers)
    hipMemsetAsync(counts, 0, (size_t)N_NODES * 4, stream);
    k_hist<<<(N_EDGES + 255) / 256, 256, 0, stream>>>(dst, counts);
    k_scan<<<1, 1024, 0, stream>>>(counts, offsets, cursor);
    k_fill<<<(N_EDGES + 255) / 256, 256, 0, stream>>>(src, dst, cursor, csr_src);

    // casts / weight prep
    k_cast<<<(N_NODES * DIM / 8 + 255) / 256, 256, 0, stream>>>(x, xb, N_NODES * DIM / 8);
    k_transW<<<(512 * 64 + 255) / 256, 256, 0, stream>>>(W1, B1);
    k_transW<<<(512 * 64 + 255) / 256, 256, 0, stream>>>(W2, B2);
    k_wtilde<<<(8 * DIM + 255) / 256, 256, 0, stream>>>(W1, a1, wt1);
    k_wtilde<<<(8 * DIM + 255) / 256, 256, 0, stream>>>(W2, a2, wt2);

    const int GEMM_BLOCKS = ((N_NODES + BM - 1) / BM) * (DIM / BN);  // 313 * 8 = 2504
    const int ALS_BLOCKS = (N_NODES + 3) / 4;                        // 5000
    const int AGG_BLOCKS = (N_NODES * 2 + 3) / 4;                    // 10000

    // ---- layer 1 ----
    k_gemm_t<<<GEMM_BLOCKS, 256, 0, stream>>>(xb, B1, h);
    k_als<<<ALS_BLOCKS, 256, 0, stream>>>(x, wt1, als, ald);
    k_agg<<<AGG_BLOCKS, 256, 0, stream>>>(offsets, csr_src, als, ald, h, b1, x, x1, xb);

    // ---- layer 2 ----
    k_gemm_t<<<GEMM_BLOCKS, 256, 0, stream>>>(xb, B2, h);
    k_als<<<ALS_BLOCKS, 256, 0, stream>>>(x1, wt2, als, ald);
    k_agg<<<AGG_BLOCKS, 256, 0, stream>>>(offsets, csr_src, als, ald, h, b2, x1, (float*)d_out, nullptr);
}